// Round 7
// baseline (452.647 us; speedup 1.0000x reference)
//
#include <hip/hip_runtime.h>

#define B_TOT 8192
#define NN 64
#define FF 32
#define ITERS 48
#define THRESH 0.35f

// ws layout:
//   [0..3]                int Tmax (atomicMax target; memset to 0 each launch)
//   [16 .. 16+B*48)       unsigned char selections per batch (393232 total)
//   [524288 .. +2MB)      float attn[B][64]          (split path only)
//   [4194304 .. +134MB)   float sims_g[B][64][64]    (split path only)
#define ATTN_OFF  (524288)
#define SIMS_OFF  (4194304)
#define WS_NEEDED (SIMS_OFF + (size_t)B_TOT * NN * NN * 4)

// ---------------------------------------------------------------------------
// PROVEN MONOLITHIC KERNEL (fallback; byte-identical to the r3 passing build).
// Its compiled fp sequence reproduces the reference selection trajectory.
// Do NOT restructure fp-bearing code here.
// ---------------------------------------------------------------------------
__global__ __launch_bounds__(64) void gat_greedy_kernel(
    const float* __restrict__ mail,
    const float* __restrict__ attn_w,
    const float* __restrict__ src_norm,
    int* __restrict__ tmax_ws,
    unsigned char* __restrict__ sels_ws)
{
    const int b = blockIdx.x;
    const int lane = threadIdx.x;

    __shared__ __align__(16) float sims[NN * 65];
    __shared__ __align__(16) float c_lds[NN];
    __shared__ float qarr[NN];
    __shared__ float sarr[NN];

    const float* __restrict__ myrow = mail + ((size_t)b * NN + lane) * FF;
    float a[FF];
#pragma unroll
    for (int k = 0; k < 8; ++k) {
        const float4 v = reinterpret_cast<const float4*>(myrow)[k];
        a[4*k+0] = v.x; a[4*k+1] = v.y; a[4*k+2] = v.z; a[4*k+3] = v.w;
    }
    const float sn = src_norm[b * NN + lane];

    float q0 = 0.f, q1 = 0.f, q2 = 0.f, q3 = 0.f;
#pragma unroll
    for (int k = 0; k < 8; ++k) {
        q0 = fmaf(a[4*k+0], a[4*k+0], q0);
        q1 = fmaf(a[4*k+1], a[4*k+1], q1);
        q2 = fmaf(a[4*k+2], a[4*k+2], q2);
        q3 = fmaf(a[4*k+3], a[4*k+3], q3);
    }
    const float q = (q0 + q1) + (q2 + q3);

    float lg = 0.f;
#pragma unroll
    for (int f = 0; f < FF; ++f) lg = fmaf(a[f], attn_w[f], lg);
    lg *= sn;

    qarr[lane] = q;
    sarr[lane] = sn;
    __syncthreads();

    float mx = lg;
#pragma unroll
    for (int off = 32; off > 0; off >>= 1)
        mx = fmaxf(mx, __shfl_xor(mx, off, 64));
    const float ex = __expf(lg - mx);
    float se = ex;
#pragma unroll
    for (int off = 32; off > 0; off >>= 1)
        se += __shfl_xor(se, off, 64);
    const float attn = ex / se;

    const float sqn = sn * sn * q;
    float dsum = 0.f;
    for (int m = 0; m < NN; ++m) {
        const float4* __restrict__ Am =
            reinterpret_cast<const float4*>(mail + ((size_t)b * NN + m) * FF);
        float g0 = 0.f, g1 = 0.f, g2 = 0.f, g3 = 0.f;
#pragma unroll
        for (int k = 0; k < 8; ++k) {
            const float4 v = Am[k];
            g0 = fmaf(a[4*k+0], v.x, g0);
            g1 = fmaf(a[4*k+1], v.y, g1);
            g2 = fmaf(a[4*k+2], v.z, g2);
            g3 = fmaf(a[4*k+3], v.w, g3);
        }
        const float g  = (g0 + g1) + (g2 + g3);
        const float sm = sarr[m];
        const float qm = qarr[m];
        const float sqm = sm * sm * qm;
        const float d2  = (sqn - 2.f * (sn * sm) * g) + sqm;
        const float d   = sqrtf(fmaxf(d2, 0.f));
        dsum += d;
        sims[lane * 65 + m] = d;
    }

    float tot = dsum;
#pragma unroll
    for (int off = 32; off > 0; off >>= 1)
        tot += __shfl_xor(tot, off, 64);
    const float meand = tot * (1.f / (float)(NN * NN));
    const float inv   = -1.f / meand;   // SIGMA = 1

    float srow[NN];
#pragma unroll
    for (int m = 0; m < NN; ++m) {
        const float d = sims[lane * 65 + m];
        const float s = __expf(d * inv);
        srow[m] = s;
        sims[lane * 65 + m] = s;
    }
#pragma unroll
    for (int m = 0; m < NN; ++m)
        asm volatile("" : "+v"(srow[m]));

    c_lds[lane] = 0.f;
    float c_reg = 0.f;
    __syncthreads();

    int firstBelow = ITERS;
    bool seenBelow = false;

    for (int t = 0; t < ITERS; ++t) {
        float gain = 0.f;
#pragma unroll
        for (int k = 0; k < 16; ++k) {
            const float4 cv = reinterpret_cast<const float4*>(c_lds)[k];
            gain += fmaxf(srow[4*k+0] - cv.x, 0.f);
            gain += fmaxf(srow[4*k+1] - cv.y, 0.f);
            gain += fmaxf(srow[4*k+2] - cv.z, 0.f);
            gain += fmaxf(srow[4*k+3] - cv.w, 0.f);
        }
        gain *= attn;

        float gv = gain; int gi = lane;
#pragma unroll
        for (int off = 32; off > 0; off >>= 1) {
            const float ov = __shfl_xor(gv, off, 64);
            const int   oi = __shfl_xor(gi, off, 64);
            if (ov > gv || (ov == gv && oi < gi)) { gv = ov; gi = oi; }
        }

        if (!seenBelow && gv < THRESH) { firstBelow = t; seenBelow = true; }
        if (lane == 0) sels_ws[(size_t)b * ITERS + t] = (unsigned char)gi;

        const float srl = sims[gi * 65 + lane];
        c_reg = fmaxf(c_reg, srl);
        c_lds[lane] = c_reg;
        __syncthreads();
    }

    if (lane == 0) atomicMax(tmax_ws, firstBelow);
}

// ---------------------------------------------------------------------------
// SPLIT PATH, PHASE 1: the proven kernel truncated after the exp pass (every
// fp instruction byte-identical), plus inert stores of s and attn to
// workspace. No selections made here.
// ---------------------------------------------------------------------------
__global__ __launch_bounds__(64) void gat_sims_kernel(
    const float* __restrict__ mail,
    const float* __restrict__ attn_w,
    const float* __restrict__ src_norm,
    float* __restrict__ sims_g,
    float* __restrict__ attn_g)
{
    const int b = blockIdx.x;
    const int lane = threadIdx.x;

    __shared__ __align__(16) float sims[NN * 65];
    __shared__ float qarr[NN];
    __shared__ float sarr[NN];

    const float* __restrict__ myrow = mail + ((size_t)b * NN + lane) * FF;
    float a[FF];
#pragma unroll
    for (int k = 0; k < 8; ++k) {
        const float4 v = reinterpret_cast<const float4*>(myrow)[k];
        a[4*k+0] = v.x; a[4*k+1] = v.y; a[4*k+2] = v.z; a[4*k+3] = v.w;
    }
    const float sn = src_norm[b * NN + lane];

    float q0 = 0.f, q1 = 0.f, q2 = 0.f, q3 = 0.f;
#pragma unroll
    for (int k = 0; k < 8; ++k) {
        q0 = fmaf(a[4*k+0], a[4*k+0], q0);
        q1 = fmaf(a[4*k+1], a[4*k+1], q1);
        q2 = fmaf(a[4*k+2], a[4*k+2], q2);
        q3 = fmaf(a[4*k+3], a[4*k+3], q3);
    }
    const float q = (q0 + q1) + (q2 + q3);

    float lg = 0.f;
#pragma unroll
    for (int f = 0; f < FF; ++f) lg = fmaf(a[f], attn_w[f], lg);
    lg *= sn;

    qarr[lane] = q;
    sarr[lane] = sn;
    __syncthreads();

    float mx = lg;
#pragma unroll
    for (int off = 32; off > 0; off >>= 1)
        mx = fmaxf(mx, __shfl_xor(mx, off, 64));
    const float ex = __expf(lg - mx);
    float se = ex;
#pragma unroll
    for (int off = 32; off > 0; off >>= 1)
        se += __shfl_xor(se, off, 64);
    const float attn = ex / se;

    const float sqn = sn * sn * q;
    float dsum = 0.f;
    for (int m = 0; m < NN; ++m) {
        const float4* __restrict__ Am =
            reinterpret_cast<const float4*>(mail + ((size_t)b * NN + m) * FF);
        float g0 = 0.f, g1 = 0.f, g2 = 0.f, g3 = 0.f;
#pragma unroll
        for (int k = 0; k < 8; ++k) {
            const float4 v = Am[k];
            g0 = fmaf(a[4*k+0], v.x, g0);
            g1 = fmaf(a[4*k+1], v.y, g1);
            g2 = fmaf(a[4*k+2], v.z, g2);
            g3 = fmaf(a[4*k+3], v.w, g3);
        }
        const float g  = (g0 + g1) + (g2 + g3);
        const float sm = sarr[m];
        const float qm = qarr[m];
        const float sqm = sm * sm * qm;
        const float d2  = (sqn - 2.f * (sn * sm) * g) + sqm;
        const float d   = sqrtf(fmaxf(d2, 0.f));
        dsum += d;
        sims[lane * 65 + m] = d;
    }

    float tot = dsum;
#pragma unroll
    for (int off = 32; off > 0; off >>= 1)
        tot += __shfl_xor(tot, off, 64);
    const float meand = tot * (1.f / (float)(NN * NN));
    const float inv   = -1.f / meand;   // SIGMA = 1

#pragma unroll
    for (int m = 0; m < NN; ++m) {
        const float d = sims[lane * 65 + m];
        const float s = __expf(d * inv);
        sims[lane * 65 + m] = s;
    }

    attn_g[b * NN + lane] = attn;
    __syncthreads();   // all rows resident in LDS before cooperative write-out

    // coalesced column-major write-out: per m, lanes store 256 B contiguous
    float* __restrict__ simsb = sims_g + (size_t)b * NN * NN;
    for (int m = 0; m < NN; ++m)
        simsb[m * NN + lane] = sims[m * 65 + lane];
}

// ---------------------------------------------------------------------------
// SPLIT PATH, PHASE 2: the greedy loop fed phase-1 bits from global (opaque
// to the compiler; zero contraction freedom in the loop's fp ops ->
// selections bitwise == proven kernel).
// Round-7 change: the per-iteration global column read simsb[gi*NN+lane]
// (HBM/L3 latency ~600-900 cy sitting inside the argmax -> cache-update
// dependency chain; confirmed by FETCH_SIZE ~= 8192*48*256B) is replaced by
// an in-register broadcast: lane gsel's srow[] holds exactly those bits
// (it loaded them from simsb row gsel), so it writes them to a 256 B LDS
// rowbuf and every lane reads rowbuf[lane] (2-way bank alias, free).
// srl bits identical -> selections identical. r6 proved occupancy is not
// the limiter, so back to 1-wave blocks (cheapest barriers).
// ---------------------------------------------------------------------------
__global__ __launch_bounds__(64) void gat_greedy2_kernel(
    const float* __restrict__ sims_g,
    const float* __restrict__ attn_g,
    int* __restrict__ tmax_ws,
    unsigned char* __restrict__ sels_ws)
{
    const int b = blockIdx.x;
    const int lane = threadIdx.x;

    __shared__ __align__(16) float c_lds[NN];
    __shared__ __align__(16) float rowbuf[NN];

    const float* __restrict__ simsb = sims_g + (size_t)b * NN * NN;

    // own row -> registers (L3-resident; written by phase 1)
    float srow[NN];
    const float4* __restrict__ rp =
        reinterpret_cast<const float4*>(simsb + (size_t)lane * NN);
#pragma unroll
    for (int k = 0; k < 16; ++k) {
        const float4 v = rp[k];
        srow[4*k+0] = v.x; srow[4*k+1] = v.y;
        srow[4*k+2] = v.z; srow[4*k+3] = v.w;
    }
#pragma unroll
    for (int m = 0; m < NN; ++m)
        asm volatile("" : "+v"(srow[m]));

    const float attn = attn_g[b * NN + lane];

    c_lds[lane] = 0.f;
    float c_reg = 0.f;
    __syncthreads();

    int firstBelow = ITERS;
    bool seenBelow = false;

    for (int t = 0; t < ITERS; ++t) {
        float gain = 0.f;
#pragma unroll
        for (int k = 0; k < 16; ++k) {
            const float4 cv = reinterpret_cast<const float4*>(c_lds)[k];
            gain += fmaxf(srow[4*k+0] - cv.x, 0.f);
            gain += fmaxf(srow[4*k+1] - cv.y, 0.f);
            gain += fmaxf(srow[4*k+2] - cv.z, 0.f);
            gain += fmaxf(srow[4*k+3] - cv.w, 0.f);
        }
        gain *= attn;

        float gv = gain; int gi = lane;
#pragma unroll
        for (int off = 32; off > 0; off >>= 1) {
            const float ov = __shfl_xor(gv, off, 64);
            const int   oi = __shfl_xor(gi, off, 64);
            if (ov > gv || (ov == gv && oi < gi)) { gv = ov; gi = oi; }
        }
        const int gsel = __builtin_amdgcn_readfirstlane(gi);

        if (!seenBelow && gv < THRESH) { firstBelow = t; seenBelow = true; }
        if (lane == 0) sels_ws[(size_t)b * ITERS + t] = (unsigned char)gsel;

        // broadcast: lane gsel's srow[] == simsb row gsel bits (loaded above)
        if (lane == gsel) {
#pragma unroll
            for (int i = 0; i < NN; ++i) rowbuf[i] = srow[i];
        }
        __syncthreads();   // rowbuf write -> read

        const float srl = rowbuf[lane];
        c_reg = fmaxf(c_reg, srl);
        c_lds[lane] = c_reg;
        __syncthreads();   // c_lds write -> next-iter gain reads
    }

    if (lane == 0) atomicMax(tmax_ws, firstBelow);
}

// ---------------------------------------------------------------------------
// ACCUM (proven r0 form)
// ---------------------------------------------------------------------------
__global__ __launch_bounds__(64) void gat_accum_kernel(
    const float* __restrict__ mail,
    const float* __restrict__ src_norm,
    const float* __restrict__ dst_norm,
    const int* __restrict__ tmax_ws,
    const unsigned char* __restrict__ sels_ws,
    float* __restrict__ out)
{
    const int lane = threadIdx.x & 31;
    const int b = blockIdx.x * 2 + (threadIdx.x >> 5);
    const int C = min(ITERS, *tmax_ws + 1);
    const unsigned char* __restrict__ sb = sels_ws + (size_t)b * ITERS;
    float acc = 0.f;
    for (int t = 0; t < C; ++t) {
        const int sel = sb[t];
        acc = fmaf(mail[((size_t)b * NN + sel) * FF + lane],
                   src_norm[b * NN + sel], acc);
    }
    out[b * FF + lane] = acc * dst_norm[b];
}

extern "C" void kernel_launch(void* const* d_in, const int* in_sizes, int n_in,
                              void* d_out, int out_size, void* d_ws, size_t ws_size,
                              hipStream_t stream)
{
    const float* mail     = (const float*)d_in[0];
    const float* attn_w   = (const float*)d_in[1];
    const float* src_norm = (const float*)d_in[2];
    const float* dst_norm = (const float*)d_in[3];
    float* out = (float*)d_out;

    int* tmax_ws = (int*)d_ws;
    unsigned char* sels_ws = (unsigned char*)d_ws + 16;

    hipMemsetAsync(d_ws, 0, 4, stream);   // zero the Tmax word

    if (ws_size >= WS_NEEDED) {
        float* attn_g = (float*)((char*)d_ws + ATTN_OFF);
        float* sims_g = (float*)((char*)d_ws + SIMS_OFF);
        gat_sims_kernel<<<dim3(B_TOT), dim3(64), 0, stream>>>(
            mail, attn_w, src_norm, sims_g, attn_g);
        gat_greedy2_kernel<<<dim3(B_TOT), dim3(64), 0, stream>>>(
            sims_g, attn_g, tmax_ws, sels_ws);
    } else {
        gat_greedy_kernel<<<dim3(B_TOT), dim3(64), 0, stream>>>(
            mail, attn_w, src_norm, tmax_ws, sels_ws);
    }
    gat_accum_kernel<<<dim3(B_TOT / 2), dim3(64), 0, stream>>>(
        mail, src_norm, dst_norm, tmax_ws, sels_ws, out);
}

// Round 8
// 313.448 us; speedup vs baseline: 1.4441x; 1.4441x over previous
//
#include <hip/hip_runtime.h>

#define B_TOT 8192
#define NN 64
#define FF 32
#define ITERS 48
#define THRESH 0.35f

// ws layout:
//   [0..3]                int Tmax (atomicMax target; memset to 0 each launch)
//   [16 .. 16+B*48)       unsigned char selections per batch (ends 393232)
//   [458752 .. +32KB)     int tstop[B] = per-batch firstBelow (split path)
//   [524288 .. +2MB)      float attn[B][64]          (split path only)
//   [4194304 .. +134MB)   float sims_g[B][64][64]    (split path only)
#define TSTOP_OFF (458752)
#define ATTN_OFF  (524288)
#define SIMS_OFF  (4194304)
#define WS_NEEDED (SIMS_OFF + (size_t)B_TOT * NN * NN * 4)

// ---------------------------------------------------------------------------
// PROVEN MONOLITHIC KERNEL (fallback; byte-identical to the r3 passing build).
// Do NOT restructure fp-bearing code here.
// ---------------------------------------------------------------------------
__global__ __launch_bounds__(64) void gat_greedy_kernel(
    const float* __restrict__ mail,
    const float* __restrict__ attn_w,
    const float* __restrict__ src_norm,
    int* __restrict__ tmax_ws,
    unsigned char* __restrict__ sels_ws)
{
    const int b = blockIdx.x;
    const int lane = threadIdx.x;

    __shared__ __align__(16) float sims[NN * 65];
    __shared__ __align__(16) float c_lds[NN];
    __shared__ float qarr[NN];
    __shared__ float sarr[NN];

    const float* __restrict__ myrow = mail + ((size_t)b * NN + lane) * FF;
    float a[FF];
#pragma unroll
    for (int k = 0; k < 8; ++k) {
        const float4 v = reinterpret_cast<const float4*>(myrow)[k];
        a[4*k+0] = v.x; a[4*k+1] = v.y; a[4*k+2] = v.z; a[4*k+3] = v.w;
    }
    const float sn = src_norm[b * NN + lane];

    float q0 = 0.f, q1 = 0.f, q2 = 0.f, q3 = 0.f;
#pragma unroll
    for (int k = 0; k < 8; ++k) {
        q0 = fmaf(a[4*k+0], a[4*k+0], q0);
        q1 = fmaf(a[4*k+1], a[4*k+1], q1);
        q2 = fmaf(a[4*k+2], a[4*k+2], q2);
        q3 = fmaf(a[4*k+3], a[4*k+3], q3);
    }
    const float q = (q0 + q1) + (q2 + q3);

    float lg = 0.f;
#pragma unroll
    for (int f = 0; f < FF; ++f) lg = fmaf(a[f], attn_w[f], lg);
    lg *= sn;

    qarr[lane] = q;
    sarr[lane] = sn;
    __syncthreads();

    float mx = lg;
#pragma unroll
    for (int off = 32; off > 0; off >>= 1)
        mx = fmaxf(mx, __shfl_xor(mx, off, 64));
    const float ex = __expf(lg - mx);
    float se = ex;
#pragma unroll
    for (int off = 32; off > 0; off >>= 1)
        se += __shfl_xor(se, off, 64);
    const float attn = ex / se;

    const float sqn = sn * sn * q;
    float dsum = 0.f;
    for (int m = 0; m < NN; ++m) {
        const float4* __restrict__ Am =
            reinterpret_cast<const float4*>(mail + ((size_t)b * NN + m) * FF);
        float g0 = 0.f, g1 = 0.f, g2 = 0.f, g3 = 0.f;
#pragma unroll
        for (int k = 0; k < 8; ++k) {
            const float4 v = Am[k];
            g0 = fmaf(a[4*k+0], v.x, g0);
            g1 = fmaf(a[4*k+1], v.y, g1);
            g2 = fmaf(a[4*k+2], v.z, g2);
            g3 = fmaf(a[4*k+3], v.w, g3);
        }
        const float g  = (g0 + g1) + (g2 + g3);
        const float sm = sarr[m];
        const float qm = qarr[m];
        const float sqm = sm * sm * qm;
        const float d2  = (sqn - 2.f * (sn * sm) * g) + sqm;
        const float d   = sqrtf(fmaxf(d2, 0.f));
        dsum += d;
        sims[lane * 65 + m] = d;
    }

    float tot = dsum;
#pragma unroll
    for (int off = 32; off > 0; off >>= 1)
        tot += __shfl_xor(tot, off, 64);
    const float meand = tot * (1.f / (float)(NN * NN));
    const float inv   = -1.f / meand;   // SIGMA = 1

    float srow[NN];
#pragma unroll
    for (int m = 0; m < NN; ++m) {
        const float d = sims[lane * 65 + m];
        const float s = __expf(d * inv);
        srow[m] = s;
        sims[lane * 65 + m] = s;
    }
#pragma unroll
    for (int m = 0; m < NN; ++m)
        asm volatile("" : "+v"(srow[m]));

    c_lds[lane] = 0.f;
    float c_reg = 0.f;
    __syncthreads();

    int firstBelow = ITERS;
    bool seenBelow = false;

    for (int t = 0; t < ITERS; ++t) {
        float gain = 0.f;
#pragma unroll
        for (int k = 0; k < 16; ++k) {
            const float4 cv = reinterpret_cast<const float4*>(c_lds)[k];
            gain += fmaxf(srow[4*k+0] - cv.x, 0.f);
            gain += fmaxf(srow[4*k+1] - cv.y, 0.f);
            gain += fmaxf(srow[4*k+2] - cv.z, 0.f);
            gain += fmaxf(srow[4*k+3] - cv.w, 0.f);
        }
        gain *= attn;

        float gv = gain; int gi = lane;
#pragma unroll
        for (int off = 32; off > 0; off >>= 1) {
            const float ov = __shfl_xor(gv, off, 64);
            const int   oi = __shfl_xor(gi, off, 64);
            if (ov > gv || (ov == gv && oi < gi)) { gv = ov; gi = oi; }
        }

        if (!seenBelow && gv < THRESH) { firstBelow = t; seenBelow = true; }
        if (lane == 0) sels_ws[(size_t)b * ITERS + t] = (unsigned char)gi;

        const float srl = sims[gi * 65 + lane];
        c_reg = fmaxf(c_reg, srl);
        c_lds[lane] = c_reg;
        __syncthreads();
    }

    if (lane == 0) atomicMax(tmax_ws, firstBelow);
}

// ---------------------------------------------------------------------------
// SPLIT PATH, PHASE 1: proven kernel truncated after the exp pass (fp
// byte-identical) + inert stores of s and attn to workspace.
// ---------------------------------------------------------------------------
__global__ __launch_bounds__(64) void gat_sims_kernel(
    const float* __restrict__ mail,
    const float* __restrict__ attn_w,
    const float* __restrict__ src_norm,
    float* __restrict__ sims_g,
    float* __restrict__ attn_g)
{
    const int b = blockIdx.x;
    const int lane = threadIdx.x;

    __shared__ __align__(16) float sims[NN * 65];
    __shared__ float qarr[NN];
    __shared__ float sarr[NN];

    const float* __restrict__ myrow = mail + ((size_t)b * NN + lane) * FF;
    float a[FF];
#pragma unroll
    for (int k = 0; k < 8; ++k) {
        const float4 v = reinterpret_cast<const float4*>(myrow)[k];
        a[4*k+0] = v.x; a[4*k+1] = v.y; a[4*k+2] = v.z; a[4*k+3] = v.w;
    }
    const float sn = src_norm[b * NN + lane];

    float q0 = 0.f, q1 = 0.f, q2 = 0.f, q3 = 0.f;
#pragma unroll
    for (int k = 0; k < 8; ++k) {
        q0 = fmaf(a[4*k+0], a[4*k+0], q0);
        q1 = fmaf(a[4*k+1], a[4*k+1], q1);
        q2 = fmaf(a[4*k+2], a[4*k+2], q2);
        q3 = fmaf(a[4*k+3], a[4*k+3], q3);
    }
    const float q = (q0 + q1) + (q2 + q3);

    float lg = 0.f;
#pragma unroll
    for (int f = 0; f < FF; ++f) lg = fmaf(a[f], attn_w[f], lg);
    lg *= sn;

    qarr[lane] = q;
    sarr[lane] = sn;
    __syncthreads();

    float mx = lg;
#pragma unroll
    for (int off = 32; off > 0; off >>= 1)
        mx = fmaxf(mx, __shfl_xor(mx, off, 64));
    const float ex = __expf(lg - mx);
    float se = ex;
#pragma unroll
    for (int off = 32; off > 0; off >>= 1)
        se += __shfl_xor(se, off, 64);
    const float attn = ex / se;

    const float sqn = sn * sn * q;
    float dsum = 0.f;
    for (int m = 0; m < NN; ++m) {
        const float4* __restrict__ Am =
            reinterpret_cast<const float4*>(mail + ((size_t)b * NN + m) * FF);
        float g0 = 0.f, g1 = 0.f, g2 = 0.f, g3 = 0.f;
#pragma unroll
        for (int k = 0; k < 8; ++k) {
            const float4 v = Am[k];
            g0 = fmaf(a[4*k+0], v.x, g0);
            g1 = fmaf(a[4*k+1], v.y, g1);
            g2 = fmaf(a[4*k+2], v.z, g2);
            g3 = fmaf(a[4*k+3], v.w, g3);
        }
        const float g  = (g0 + g1) + (g2 + g3);
        const float sm = sarr[m];
        const float qm = qarr[m];
        const float sqm = sm * sm * qm;
        const float d2  = (sqn - 2.f * (sn * sm) * g) + sqm;
        const float d   = sqrtf(fmaxf(d2, 0.f));
        dsum += d;
        sims[lane * 65 + m] = d;
    }

    float tot = dsum;
#pragma unroll
    for (int off = 32; off > 0; off >>= 1)
        tot += __shfl_xor(tot, off, 64);
    const float meand = tot * (1.f / (float)(NN * NN));
    const float inv   = -1.f / meand;   // SIGMA = 1

#pragma unroll
    for (int m = 0; m < NN; ++m) {
        const float d = sims[lane * 65 + m];
        const float s = __expf(d * inv);
        sims[lane * 65 + m] = s;
    }

    attn_g[b * NN + lane] = attn;
    __syncthreads();

    float* __restrict__ simsb = sims_g + (size_t)b * NN * NN;
    for (int m = 0; m < NN; ++m)
        simsb[m * NN + lane] = sims[m * 65 + lane];
}

// ---------------------------------------------------------------------------
// SPLIT PATH, PASS A: the r5 greedy2 kernel (best measured: 210us, global
// column read) + early exit. gv is wave-uniform after the butterfly, and
// per-batch max gain is monotone non-increasing (cache only grows), so the
// block can stop right after recording the selection at its own firstBelow.
// The loop body has NO contractible/reassociable fp (add-of-max accumulator,
// lone mul, compares, fmax) -> the break cannot perturb per-iteration bits.
// ---------------------------------------------------------------------------
__global__ __launch_bounds__(64) void gat_greedyA_kernel(
    const float* __restrict__ sims_g,
    const float* __restrict__ attn_g,
    int* __restrict__ tmax_ws,
    int* __restrict__ tstop_ws,
    unsigned char* __restrict__ sels_ws)
{
    const int b = blockIdx.x;
    const int lane = threadIdx.x;

    __shared__ __align__(16) float c_lds[NN];

    const float* __restrict__ simsb = sims_g + (size_t)b * NN * NN;

    float srow[NN];
    const float4* __restrict__ rp =
        reinterpret_cast<const float4*>(simsb + (size_t)lane * NN);
#pragma unroll
    for (int k = 0; k < 16; ++k) {
        const float4 v = rp[k];
        srow[4*k+0] = v.x; srow[4*k+1] = v.y;
        srow[4*k+2] = v.z; srow[4*k+3] = v.w;
    }
#pragma unroll
    for (int m = 0; m < NN; ++m)
        asm volatile("" : "+v"(srow[m]));

    const float attn = attn_g[b * NN + lane];

    c_lds[lane] = 0.f;
    float c_reg = 0.f;
    __syncthreads();

    int firstBelow = ITERS;

    for (int t = 0; t < ITERS; ++t) {
        float gain = 0.f;
#pragma unroll
        for (int k = 0; k < 16; ++k) {
            const float4 cv = reinterpret_cast<const float4*>(c_lds)[k];
            gain += fmaxf(srow[4*k+0] - cv.x, 0.f);
            gain += fmaxf(srow[4*k+1] - cv.y, 0.f);
            gain += fmaxf(srow[4*k+2] - cv.z, 0.f);
            gain += fmaxf(srow[4*k+3] - cv.w, 0.f);
        }
        gain *= attn;

        float gv = gain; int gi = lane;
#pragma unroll
        for (int off = 32; off > 0; off >>= 1) {
            const float ov = __shfl_xor(gv, off, 64);
            const int   oi = __shfl_xor(gi, off, 64);
            if (ov > gv || (ov == gv && oi < gi)) { gv = ov; gi = oi; }
        }

        if (lane == 0) sels_ws[(size_t)b * ITERS + t] = (unsigned char)gi;

        const float srl = simsb[gi * NN + lane];
        c_reg = fmaxf(c_reg, srl);
        c_lds[lane] = c_reg;
        __syncthreads();

        if (gv < THRESH) { firstBelow = t; break; }   // wave-uniform
    }

    if (lane == 0) {
        atomicMax(tmax_ws, firstBelow);
        tstop_ws[b] = firstBelow;
    }
}

// ---------------------------------------------------------------------------
// SPLIT PATH, PASS B: resume batches whose firstBelow < min(47, Tmax).
// Cache c is reconstructed bit-exactly by replaying the recorded selections
// in original order (same fmax sequence, same simsb bits); then the loop
// body runs identically for t = fb+1 .. min(47, Tmax).
// ---------------------------------------------------------------------------
__global__ __launch_bounds__(64) void gat_greedyB_kernel(
    const float* __restrict__ sims_g,
    const float* __restrict__ attn_g,
    const int* __restrict__ tmax_ws,
    const int* __restrict__ tstop_ws,
    unsigned char* __restrict__ sels_ws)
{
    const int b = blockIdx.x;
    const int lane = threadIdx.x;

    const int fb   = tstop_ws[b];
    const int tEnd = min(ITERS - 1, *tmax_ws);   // last t whose selection is consumed
    if (fb >= tEnd) return;                      // pass A already covered 0..tEnd

    __shared__ __align__(16) float c_lds[NN];

    const float* __restrict__ simsb = sims_g + (size_t)b * NN * NN;

    float srow[NN];
    const float4* __restrict__ rp =
        reinterpret_cast<const float4*>(simsb + (size_t)lane * NN);
#pragma unroll
    for (int k = 0; k < 16; ++k) {
        const float4 v = rp[k];
        srow[4*k+0] = v.x; srow[4*k+1] = v.y;
        srow[4*k+2] = v.z; srow[4*k+3] = v.w;
    }
#pragma unroll
    for (int m = 0; m < NN; ++m)
        asm volatile("" : "+v"(srow[m]));

    const float attn = attn_g[b * NN + lane];

    // replay selections 0..fb to reconstruct c (same fmax order as pass A)
    float c_reg = 0.f;
    const unsigned char* __restrict__ sb = sels_ws + (size_t)b * ITERS;
    for (int j = 0; j <= fb; ++j) {
        const int sel = sb[j];
        c_reg = fmaxf(c_reg, simsb[sel * NN + lane]);
    }
    c_lds[lane] = c_reg;
    __syncthreads();

    for (int t = fb + 1; t <= tEnd; ++t) {
        float gain = 0.f;
#pragma unroll
        for (int k = 0; k < 16; ++k) {
            const float4 cv = reinterpret_cast<const float4*>(c_lds)[k];
            gain += fmaxf(srow[4*k+0] - cv.x, 0.f);
            gain += fmaxf(srow[4*k+1] - cv.y, 0.f);
            gain += fmaxf(srow[4*k+2] - cv.z, 0.f);
            gain += fmaxf(srow[4*k+3] - cv.w, 0.f);
        }
        gain *= attn;

        float gv = gain; int gi = lane;
#pragma unroll
        for (int off = 32; off > 0; off >>= 1) {
            const float ov = __shfl_xor(gv, off, 64);
            const int   oi = __shfl_xor(gi, off, 64);
            if (ov > gv || (ov == gv && oi < gi)) { gv = ov; gi = oi; }
        }

        if (lane == 0) sels_ws[(size_t)b * ITERS + t] = (unsigned char)gi;

        const float srl = simsb[gi * NN + lane];
        c_reg = fmaxf(c_reg, srl);
        c_lds[lane] = c_reg;
        __syncthreads();
    }
}

// ---------------------------------------------------------------------------
// ACCUM (proven r0 form)
// ---------------------------------------------------------------------------
__global__ __launch_bounds__(64) void gat_accum_kernel(
    const float* __restrict__ mail,
    const float* __restrict__ src_norm,
    const float* __restrict__ dst_norm,
    const int* __restrict__ tmax_ws,
    const unsigned char* __restrict__ sels_ws,
    float* __restrict__ out)
{
    const int lane = threadIdx.x & 31;
    const int b = blockIdx.x * 2 + (threadIdx.x >> 5);
    const int C = min(ITERS, *tmax_ws + 1);
    const unsigned char* __restrict__ sb = sels_ws + (size_t)b * ITERS;
    float acc = 0.f;
    for (int t = 0; t < C; ++t) {
        const int sel = sb[t];
        acc = fmaf(mail[((size_t)b * NN + sel) * FF + lane],
                   src_norm[b * NN + sel], acc);
    }
    out[b * FF + lane] = acc * dst_norm[b];
}

extern "C" void kernel_launch(void* const* d_in, const int* in_sizes, int n_in,
                              void* d_out, int out_size, void* d_ws, size_t ws_size,
                              hipStream_t stream)
{
    const float* mail     = (const float*)d_in[0];
    const float* attn_w   = (const float*)d_in[1];
    const float* src_norm = (const float*)d_in[2];
    const float* dst_norm = (const float*)d_in[3];
    float* out = (float*)d_out;

    int* tmax_ws = (int*)d_ws;
    unsigned char* sels_ws = (unsigned char*)d_ws + 16;

    hipMemsetAsync(d_ws, 0, 4, stream);   // zero the Tmax word

    if (ws_size >= WS_NEEDED) {
        int*   tstop_ws = (int*)((char*)d_ws + TSTOP_OFF);
        float* attn_g   = (float*)((char*)d_ws + ATTN_OFF);
        float* sims_g   = (float*)((char*)d_ws + SIMS_OFF);
        gat_sims_kernel<<<dim3(B_TOT), dim3(64), 0, stream>>>(
            mail, attn_w, src_norm, sims_g, attn_g);
        gat_greedyA_kernel<<<dim3(B_TOT), dim3(64), 0, stream>>>(
            sims_g, attn_g, tmax_ws, tstop_ws, sels_ws);
        gat_greedyB_kernel<<<dim3(B_TOT), dim3(64), 0, stream>>>(
            sims_g, attn_g, tmax_ws, tstop_ws, sels_ws);
    } else {
        gat_greedy_kernel<<<dim3(B_TOT), dim3(64), 0, stream>>>(
            mail, attn_w, src_norm, tmax_ws, sels_ws);
    }
    gat_accum_kernel<<<dim3(B_TOT / 2), dim3(64), 0, stream>>>(
        mail, src_norm, dst_norm, tmax_ws, sels_ws, out);
}

// Round 9
// 252.888 us; speedup vs baseline: 1.7899x; 1.2395x over previous
//
#include <hip/hip_runtime.h>

#define B_TOT 8192
#define NN 64
#define FF 32
#define ITERS 48
#define THRESH 0.35f

// ws layout:
//   [0..3]                int Tmax (atomicMax target; memset to 0 each launch)
//   [16 .. 16+B*48)       unsigned char selections per batch (ends 393232)
//   [458752 .. +32KB)     int tstop[B] = per-batch firstBelow (split path)
//   [524288 .. +2MB)      float attn[B][64]          (split path only)
//   [4194304 .. +134MB)   float sims_g[B][64][64]    (split path only)
#define TSTOP_OFF (458752)
#define ATTN_OFF  (524288)
#define SIMS_OFF  (4194304)
#define WS_NEEDED (SIMS_OFF + (size_t)B_TOT * NN * NN * 4)

// ---------------------------------------------------------------------------
// PROVEN MONOLITHIC KERNEL (fallback for small ws; byte-identical to the r3
// passing build). Do NOT restructure fp-bearing code here.
// ---------------------------------------------------------------------------
__global__ __launch_bounds__(64) void gat_greedy_kernel(
    const float* __restrict__ mail,
    const float* __restrict__ attn_w,
    const float* __restrict__ src_norm,
    int* __restrict__ tmax_ws,
    unsigned char* __restrict__ sels_ws)
{
    const int b = blockIdx.x;
    const int lane = threadIdx.x;

    __shared__ __align__(16) float sims[NN * 65];
    __shared__ __align__(16) float c_lds[NN];
    __shared__ float qarr[NN];
    __shared__ float sarr[NN];

    const float* __restrict__ myrow = mail + ((size_t)b * NN + lane) * FF;
    float a[FF];
#pragma unroll
    for (int k = 0; k < 8; ++k) {
        const float4 v = reinterpret_cast<const float4*>(myrow)[k];
        a[4*k+0] = v.x; a[4*k+1] = v.y; a[4*k+2] = v.z; a[4*k+3] = v.w;
    }
    const float sn = src_norm[b * NN + lane];

    float q0 = 0.f, q1 = 0.f, q2 = 0.f, q3 = 0.f;
#pragma unroll
    for (int k = 0; k < 8; ++k) {
        q0 = fmaf(a[4*k+0], a[4*k+0], q0);
        q1 = fmaf(a[4*k+1], a[4*k+1], q1);
        q2 = fmaf(a[4*k+2], a[4*k+2], q2);
        q3 = fmaf(a[4*k+3], a[4*k+3], q3);
    }
    const float q = (q0 + q1) + (q2 + q3);

    float lg = 0.f;
#pragma unroll
    for (int f = 0; f < FF; ++f) lg = fmaf(a[f], attn_w[f], lg);
    lg *= sn;

    qarr[lane] = q;
    sarr[lane] = sn;
    __syncthreads();

    float mx = lg;
#pragma unroll
    for (int off = 32; off > 0; off >>= 1)
        mx = fmaxf(mx, __shfl_xor(mx, off, 64));
    const float ex = __expf(lg - mx);
    float se = ex;
#pragma unroll
    for (int off = 32; off > 0; off >>= 1)
        se += __shfl_xor(se, off, 64);
    const float attn = ex / se;

    const float sqn = sn * sn * q;
    float dsum = 0.f;
    for (int m = 0; m < NN; ++m) {
        const float4* __restrict__ Am =
            reinterpret_cast<const float4*>(mail + ((size_t)b * NN + m) * FF);
        float g0 = 0.f, g1 = 0.f, g2 = 0.f, g3 = 0.f;
#pragma unroll
        for (int k = 0; k < 8; ++k) {
            const float4 v = Am[k];
            g0 = fmaf(a[4*k+0], v.x, g0);
            g1 = fmaf(a[4*k+1], v.y, g1);
            g2 = fmaf(a[4*k+2], v.z, g2);
            g3 = fmaf(a[4*k+3], v.w, g3);
        }
        const float g  = (g0 + g1) + (g2 + g3);
        const float sm = sarr[m];
        const float qm = qarr[m];
        const float sqm = sm * sm * qm;
        const float d2  = (sqn - 2.f * (sn * sm) * g) + sqm;
        const float d   = sqrtf(fmaxf(d2, 0.f));
        dsum += d;
        sims[lane * 65 + m] = d;
    }

    float tot = dsum;
#pragma unroll
    for (int off = 32; off > 0; off >>= 1)
        tot += __shfl_xor(tot, off, 64);
    const float meand = tot * (1.f / (float)(NN * NN));
    const float inv   = -1.f / meand;   // SIGMA = 1

    float srow[NN];
#pragma unroll
    for (int m = 0; m < NN; ++m) {
        const float d = sims[lane * 65 + m];
        const float s = __expf(d * inv);
        srow[m] = s;
        sims[lane * 65 + m] = s;
    }
#pragma unroll
    for (int m = 0; m < NN; ++m)
        asm volatile("" : "+v"(srow[m]));

    c_lds[lane] = 0.f;
    float c_reg = 0.f;
    __syncthreads();

    int firstBelow = ITERS;
    bool seenBelow = false;

    for (int t = 0; t < ITERS; ++t) {
        float gain = 0.f;
#pragma unroll
        for (int k = 0; k < 16; ++k) {
            const float4 cv = reinterpret_cast<const float4*>(c_lds)[k];
            gain += fmaxf(srow[4*k+0] - cv.x, 0.f);
            gain += fmaxf(srow[4*k+1] - cv.y, 0.f);
            gain += fmaxf(srow[4*k+2] - cv.z, 0.f);
            gain += fmaxf(srow[4*k+3] - cv.w, 0.f);
        }
        gain *= attn;

        float gv = gain; int gi = lane;
#pragma unroll
        for (int off = 32; off > 0; off >>= 1) {
            const float ov = __shfl_xor(gv, off, 64);
            const int   oi = __shfl_xor(gi, off, 64);
            if (ov > gv || (ov == gv && oi < gi)) { gv = ov; gi = oi; }
        }

        if (!seenBelow && gv < THRESH) { firstBelow = t; seenBelow = true; }
        if (lane == 0) sels_ws[(size_t)b * ITERS + t] = (unsigned char)gi;

        const float srl = sims[gi * 65 + lane];
        c_reg = fmaxf(c_reg, srl);
        c_lds[lane] = c_reg;
        __syncthreads();
    }

    if (lane == 0) atomicMax(tmax_ws, firstBelow);
}

// ---------------------------------------------------------------------------
// FUSED PASS A: the proven monolith with three bit-safe deltas:
//   (1) wave-uniform break after the cache update (r8-proven transform:
//       greedy body has no contractible/reassociable fp),
//   (2) tstop[b] record for pass B,
//   (3) CONDITIONAL spill of sims (from intact LDS) + attn to workspace,
//       only for batches pass B might resume (fb <= 46).
// E[iterations] ~= 2 (r8 VALUBusy evidence), so the greedy part is nearly
// free; this deletes the separate sims kernel and pass A's 68 MB srow
// reload entirely. Phase-1 fp source is byte-identical to the proven build.
// ---------------------------------------------------------------------------
__global__ __launch_bounds__(64) void gat_fusedA_kernel(
    const float* __restrict__ mail,
    const float* __restrict__ attn_w,
    const float* __restrict__ src_norm,
    int* __restrict__ tmax_ws,
    int* __restrict__ tstop_ws,
    unsigned char* __restrict__ sels_ws,
    float* __restrict__ sims_g,
    float* __restrict__ attn_g)
{
    const int b = blockIdx.x;
    const int lane = threadIdx.x;

    __shared__ __align__(16) float sims[NN * 65];
    __shared__ __align__(16) float c_lds[NN];
    __shared__ float qarr[NN];
    __shared__ float sarr[NN];

    const float* __restrict__ myrow = mail + ((size_t)b * NN + lane) * FF;
    float a[FF];
#pragma unroll
    for (int k = 0; k < 8; ++k) {
        const float4 v = reinterpret_cast<const float4*>(myrow)[k];
        a[4*k+0] = v.x; a[4*k+1] = v.y; a[4*k+2] = v.z; a[4*k+3] = v.w;
    }
    const float sn = src_norm[b * NN + lane];

    float q0 = 0.f, q1 = 0.f, q2 = 0.f, q3 = 0.f;
#pragma unroll
    for (int k = 0; k < 8; ++k) {
        q0 = fmaf(a[4*k+0], a[4*k+0], q0);
        q1 = fmaf(a[4*k+1], a[4*k+1], q1);
        q2 = fmaf(a[4*k+2], a[4*k+2], q2);
        q3 = fmaf(a[4*k+3], a[4*k+3], q3);
    }
    const float q = (q0 + q1) + (q2 + q3);

    float lg = 0.f;
#pragma unroll
    for (int f = 0; f < FF; ++f) lg = fmaf(a[f], attn_w[f], lg);
    lg *= sn;

    qarr[lane] = q;
    sarr[lane] = sn;
    __syncthreads();

    float mx = lg;
#pragma unroll
    for (int off = 32; off > 0; off >>= 1)
        mx = fmaxf(mx, __shfl_xor(mx, off, 64));
    const float ex = __expf(lg - mx);
    float se = ex;
#pragma unroll
    for (int off = 32; off > 0; off >>= 1)
        se += __shfl_xor(se, off, 64);
    const float attn = ex / se;

    const float sqn = sn * sn * q;
    float dsum = 0.f;
    for (int m = 0; m < NN; ++m) {
        const float4* __restrict__ Am =
            reinterpret_cast<const float4*>(mail + ((size_t)b * NN + m) * FF);
        float g0 = 0.f, g1 = 0.f, g2 = 0.f, g3 = 0.f;
#pragma unroll
        for (int k = 0; k < 8; ++k) {
            const float4 v = Am[k];
            g0 = fmaf(a[4*k+0], v.x, g0);
            g1 = fmaf(a[4*k+1], v.y, g1);
            g2 = fmaf(a[4*k+2], v.z, g2);
            g3 = fmaf(a[4*k+3], v.w, g3);
        }
        const float g  = (g0 + g1) + (g2 + g3);
        const float sm = sarr[m];
        const float qm = qarr[m];
        const float sqm = sm * sm * qm;
        const float d2  = (sqn - 2.f * (sn * sm) * g) + sqm;
        const float d   = sqrtf(fmaxf(d2, 0.f));
        dsum += d;
        sims[lane * 65 + m] = d;
    }

    float tot = dsum;
#pragma unroll
    for (int off = 32; off > 0; off >>= 1)
        tot += __shfl_xor(tot, off, 64);
    const float meand = tot * (1.f / (float)(NN * NN));
    const float inv   = -1.f / meand;   // SIGMA = 1

    float srow[NN];
#pragma unroll
    for (int m = 0; m < NN; ++m) {
        const float d = sims[lane * 65 + m];
        const float s = __expf(d * inv);
        srow[m] = s;
        sims[lane * 65 + m] = s;
    }
#pragma unroll
    for (int m = 0; m < NN; ++m)
        asm volatile("" : "+v"(srow[m]));

    c_lds[lane] = 0.f;
    float c_reg = 0.f;
    __syncthreads();

    int firstBelow = ITERS;

    for (int t = 0; t < ITERS; ++t) {
        float gain = 0.f;
#pragma unroll
        for (int k = 0; k < 16; ++k) {
            const float4 cv = reinterpret_cast<const float4*>(c_lds)[k];
            gain += fmaxf(srow[4*k+0] - cv.x, 0.f);
            gain += fmaxf(srow[4*k+1] - cv.y, 0.f);
            gain += fmaxf(srow[4*k+2] - cv.z, 0.f);
            gain += fmaxf(srow[4*k+3] - cv.w, 0.f);
        }
        gain *= attn;

        float gv = gain; int gi = lane;
#pragma unroll
        for (int off = 32; off > 0; off >>= 1) {
            const float ov = __shfl_xor(gv, off, 64);
            const int   oi = __shfl_xor(gi, off, 64);
            if (ov > gv || (ov == gv && oi < gi)) { gv = ov; gi = oi; }
        }

        if (lane == 0) sels_ws[(size_t)b * ITERS + t] = (unsigned char)gi;

        const float srl = sims[gi * 65 + lane];
        c_reg = fmaxf(c_reg, srl);
        c_lds[lane] = c_reg;
        __syncthreads();

        if (gv < THRESH) { firstBelow = t; break; }   // wave-uniform
    }

    if (lane == 0) {
        atomicMax(tmax_ws, firstBelow);
        tstop_ws[b] = firstBelow;
    }

    // spill sims (s values; LDS intact) + attn for batches pass B may resume:
    // resume requires fb < tEnd <= 47, i.e. fb <= 46.
    if (firstBelow < ITERS - 1) {
        attn_g[b * NN + lane] = attn;
        float* __restrict__ simsb = sims_g + (size_t)b * NN * NN;
        for (int m = 0; m < NN; ++m)
            simsb[m * NN + lane] = sims[m * 65 + lane];
    }
}

// ---------------------------------------------------------------------------
// PASS B (unchanged from r8, which passed): resume batches whose
// firstBelow < min(47, Tmax). Cache c is reconstructed exactly by replaying
// the recorded selections (fmax is exact: no rounding, order-free); then the
// loop body runs identically for t = fb+1 .. min(47, Tmax).
// ---------------------------------------------------------------------------
__global__ __launch_bounds__(64) void gat_greedyB_kernel(
    const float* __restrict__ sims_g,
    const float* __restrict__ attn_g,
    const int* __restrict__ tmax_ws,
    const int* __restrict__ tstop_ws,
    unsigned char* __restrict__ sels_ws)
{
    const int b = blockIdx.x;
    const int lane = threadIdx.x;

    const int fb   = tstop_ws[b];
    const int tEnd = min(ITERS - 1, *tmax_ws);   // last t whose selection is consumed
    if (fb >= tEnd) return;                      // pass A already covered 0..tEnd

    __shared__ __align__(16) float c_lds[NN];

    const float* __restrict__ simsb = sims_g + (size_t)b * NN * NN;

    float srow[NN];
    const float4* __restrict__ rp =
        reinterpret_cast<const float4*>(simsb + (size_t)lane * NN);
#pragma unroll
    for (int k = 0; k < 16; ++k) {
        const float4 v = rp[k];
        srow[4*k+0] = v.x; srow[4*k+1] = v.y;
        srow[4*k+2] = v.z; srow[4*k+3] = v.w;
    }
#pragma unroll
    for (int m = 0; m < NN; ++m)
        asm volatile("" : "+v"(srow[m]));

    const float attn = attn_g[b * NN + lane];

    // replay selections 0..fb to reconstruct c (fmax: exact, order-free)
    float c_reg = 0.f;
    const unsigned char* __restrict__ sb = sels_ws + (size_t)b * ITERS;
    for (int j = 0; j <= fb; ++j) {
        const int sel = sb[j];
        c_reg = fmaxf(c_reg, simsb[sel * NN + lane]);
    }
    c_lds[lane] = c_reg;
    __syncthreads();

    for (int t = fb + 1; t <= tEnd; ++t) {
        float gain = 0.f;
#pragma unroll
        for (int k = 0; k < 16; ++k) {
            const float4 cv = reinterpret_cast<const float4*>(c_lds)[k];
            gain += fmaxf(srow[4*k+0] - cv.x, 0.f);
            gain += fmaxf(srow[4*k+1] - cv.y, 0.f);
            gain += fmaxf(srow[4*k+2] - cv.z, 0.f);
            gain += fmaxf(srow[4*k+3] - cv.w, 0.f);
        }
        gain *= attn;

        float gv = gain; int gi = lane;
#pragma unroll
        for (int off = 32; off > 0; off >>= 1) {
            const float ov = __shfl_xor(gv, off, 64);
            const int   oi = __shfl_xor(gi, off, 64);
            if (ov > gv || (ov == gv && oi < gi)) { gv = ov; gi = oi; }
        }

        if (lane == 0) sels_ws[(size_t)b * ITERS + t] = (unsigned char)gi;

        const float srl = simsb[gi * NN + lane];
        c_reg = fmaxf(c_reg, srl);
        c_lds[lane] = c_reg;
        __syncthreads();
    }
}

// ---------------------------------------------------------------------------
// ACCUM (proven r0 form)
// ---------------------------------------------------------------------------
__global__ __launch_bounds__(64) void gat_accum_kernel(
    const float* __restrict__ mail,
    const float* __restrict__ src_norm,
    const float* __restrict__ dst_norm,
    const int* __restrict__ tmax_ws,
    const unsigned char* __restrict__ sels_ws,
    float* __restrict__ out)
{
    const int lane = threadIdx.x & 31;
    const int b = blockIdx.x * 2 + (threadIdx.x >> 5);
    const int C = min(ITERS, *tmax_ws + 1);
    const unsigned char* __restrict__ sb = sels_ws + (size_t)b * ITERS;
    float acc = 0.f;
    for (int t = 0; t < C; ++t) {
        const int sel = sb[t];
        acc = fmaf(mail[((size_t)b * NN + sel) * FF + lane],
                   src_norm[b * NN + sel], acc);
    }
    out[b * FF + lane] = acc * dst_norm[b];
}

extern "C" void kernel_launch(void* const* d_in, const int* in_sizes, int n_in,
                              void* d_out, int out_size, void* d_ws, size_t ws_size,
                              hipStream_t stream)
{
    const float* mail     = (const float*)d_in[0];
    const float* attn_w   = (const float*)d_in[1];
    const float* src_norm = (const float*)d_in[2];
    const float* dst_norm = (const float*)d_in[3];
    float* out = (float*)d_out;

    int* tmax_ws = (int*)d_ws;
    unsigned char* sels_ws = (unsigned char*)d_ws + 16;

    hipMemsetAsync(d_ws, 0, 4, stream);   // zero the Tmax word

    if (ws_size >= WS_NEEDED) {
        int*   tstop_ws = (int*)((char*)d_ws + TSTOP_OFF);
        float* attn_g   = (float*)((char*)d_ws + ATTN_OFF);
        float* sims_g   = (float*)((char*)d_ws + SIMS_OFF);
        gat_fusedA_kernel<<<dim3(B_TOT), dim3(64), 0, stream>>>(
            mail, attn_w, src_norm, tmax_ws, tstop_ws, sels_ws, sims_g, attn_g);
        gat_greedyB_kernel<<<dim3(B_TOT), dim3(64), 0, stream>>>(
            sims_g, attn_g, tmax_ws, tstop_ws, sels_ws);
    } else {
        gat_greedy_kernel<<<dim3(B_TOT), dim3(64), 0, stream>>>(
            mail, attn_w, src_norm, tmax_ws, sels_ws);
    }
    gat_accum_kernel<<<dim3(B_TOT / 2), dim3(64), 0, stream>>>(
        mail, src_norm, dst_norm, tmax_ws, sels_ws, out);
}

// Round 10
// 237.782 us; speedup vs baseline: 1.9036x; 1.0635x over previous
//
#include <hip/hip_runtime.h>

#define B_TOT 8192
#define NN 64
#define FF 32
#define ITERS 48
#define THRESH 0.35f

// ws layout:
//   [0..3]                int Tmax (atomicMax target; memset to 0 each launch)
//   [16 .. 16+B*48)       unsigned char selections per batch (ends 393232)
//   [458752 .. +32KB)     int tstop[B] = per-batch firstBelow (split path)
//   [524288 .. +2MB)      float attn[B][64]          (split path only)
//   [4194304 .. +134MB)   float sims_g[B][64][64]    (split path only)
#define TSTOP_OFF (458752)
#define ATTN_OFF  (524288)
#define SIMS_OFF  (4194304)
#define WS_NEEDED (SIMS_OFF + (size_t)B_TOT * NN * NN * 4)

// ---------------------------------------------------------------------------
// PROVEN MONOLITHIC KERNEL (fallback for small ws; byte-identical to the r3
// passing build). Do NOT restructure fp-bearing code here.
// ---------------------------------------------------------------------------
__global__ __launch_bounds__(64) void gat_greedy_kernel(
    const float* __restrict__ mail,
    const float* __restrict__ attn_w,
    const float* __restrict__ src_norm,
    int* __restrict__ tmax_ws,
    unsigned char* __restrict__ sels_ws)
{
    const int b = blockIdx.x;
    const int lane = threadIdx.x;

    __shared__ __align__(16) float sims[NN * 65];
    __shared__ __align__(16) float c_lds[NN];
    __shared__ float qarr[NN];
    __shared__ float sarr[NN];

    const float* __restrict__ myrow = mail + ((size_t)b * NN + lane) * FF;
    float a[FF];
#pragma unroll
    for (int k = 0; k < 8; ++k) {
        const float4 v = reinterpret_cast<const float4*>(myrow)[k];
        a[4*k+0] = v.x; a[4*k+1] = v.y; a[4*k+2] = v.z; a[4*k+3] = v.w;
    }
    const float sn = src_norm[b * NN + lane];

    float q0 = 0.f, q1 = 0.f, q2 = 0.f, q3 = 0.f;
#pragma unroll
    for (int k = 0; k < 8; ++k) {
        q0 = fmaf(a[4*k+0], a[4*k+0], q0);
        q1 = fmaf(a[4*k+1], a[4*k+1], q1);
        q2 = fmaf(a[4*k+2], a[4*k+2], q2);
        q3 = fmaf(a[4*k+3], a[4*k+3], q3);
    }
    const float q = (q0 + q1) + (q2 + q3);

    float lg = 0.f;
#pragma unroll
    for (int f = 0; f < FF; ++f) lg = fmaf(a[f], attn_w[f], lg);
    lg *= sn;

    qarr[lane] = q;
    sarr[lane] = sn;
    __syncthreads();

    float mx = lg;
#pragma unroll
    for (int off = 32; off > 0; off >>= 1)
        mx = fmaxf(mx, __shfl_xor(mx, off, 64));
    const float ex = __expf(lg - mx);
    float se = ex;
#pragma unroll
    for (int off = 32; off > 0; off >>= 1)
        se += __shfl_xor(se, off, 64);
    const float attn = ex / se;

    const float sqn = sn * sn * q;
    float dsum = 0.f;
    for (int m = 0; m < NN; ++m) {
        const float4* __restrict__ Am =
            reinterpret_cast<const float4*>(mail + ((size_t)b * NN + m) * FF);
        float g0 = 0.f, g1 = 0.f, g2 = 0.f, g3 = 0.f;
#pragma unroll
        for (int k = 0; k < 8; ++k) {
            const float4 v = Am[k];
            g0 = fmaf(a[4*k+0], v.x, g0);
            g1 = fmaf(a[4*k+1], v.y, g1);
            g2 = fmaf(a[4*k+2], v.z, g2);
            g3 = fmaf(a[4*k+3], v.w, g3);
        }
        const float g  = (g0 + g1) + (g2 + g3);
        const float sm = sarr[m];
        const float qm = qarr[m];
        const float sqm = sm * sm * qm;
        const float d2  = (sqn - 2.f * (sn * sm) * g) + sqm;
        const float d   = sqrtf(fmaxf(d2, 0.f));
        dsum += d;
        sims[lane * 65 + m] = d;
    }

    float tot = dsum;
#pragma unroll
    for (int off = 32; off > 0; off >>= 1)
        tot += __shfl_xor(tot, off, 64);
    const float meand = tot * (1.f / (float)(NN * NN));
    const float inv   = -1.f / meand;   // SIGMA = 1

    float srow[NN];
#pragma unroll
    for (int m = 0; m < NN; ++m) {
        const float d = sims[lane * 65 + m];
        const float s = __expf(d * inv);
        srow[m] = s;
        sims[lane * 65 + m] = s;
    }
#pragma unroll
    for (int m = 0; m < NN; ++m)
        asm volatile("" : "+v"(srow[m]));

    c_lds[lane] = 0.f;
    float c_reg = 0.f;
    __syncthreads();

    int firstBelow = ITERS;
    bool seenBelow = false;

    for (int t = 0; t < ITERS; ++t) {
        float gain = 0.f;
#pragma unroll
        for (int k = 0; k < 16; ++k) {
            const float4 cv = reinterpret_cast<const float4*>(c_lds)[k];
            gain += fmaxf(srow[4*k+0] - cv.x, 0.f);
            gain += fmaxf(srow[4*k+1] - cv.y, 0.f);
            gain += fmaxf(srow[4*k+2] - cv.z, 0.f);
            gain += fmaxf(srow[4*k+3] - cv.w, 0.f);
        }
        gain *= attn;

        float gv = gain; int gi = lane;
#pragma unroll
        for (int off = 32; off > 0; off >>= 1) {
            const float ov = __shfl_xor(gv, off, 64);
            const int   oi = __shfl_xor(gi, off, 64);
            if (ov > gv || (ov == gv && oi < gi)) { gv = ov; gi = oi; }
        }

        if (!seenBelow && gv < THRESH) { firstBelow = t; seenBelow = true; }
        if (lane == 0) sels_ws[(size_t)b * ITERS + t] = (unsigned char)gi;

        const float srl = sims[gi * 65 + lane];
        c_reg = fmaxf(c_reg, srl);
        c_lds[lane] = c_reg;
        __syncthreads();
    }

    if (lane == 0) atomicMax(tmax_ws, firstBelow);
}

// ---------------------------------------------------------------------------
// FUSED PASS A (r9-proven, one scheduling delta): phase-1 fp byte-identical;
// wave-uniform break (r8-proven); spill of sims+attn HOISTED before the
// greedy loop and made unconditional (r9's WRITE_SIZE showed ~all batches
// spill anyway) -- the fire-and-forget stores drain while the ~2 greedy
// iterations run, instead of serializing after them. Zero fp impact.
// ---------------------------------------------------------------------------
__global__ __launch_bounds__(64) void gat_fusedA_kernel(
    const float* __restrict__ mail,
    const float* __restrict__ attn_w,
    const float* __restrict__ src_norm,
    int* __restrict__ tmax_ws,
    int* __restrict__ tstop_ws,
    unsigned char* __restrict__ sels_ws,
    float* __restrict__ sims_g,
    float* __restrict__ attn_g)
{
    const int b = blockIdx.x;
    const int lane = threadIdx.x;

    __shared__ __align__(16) float sims[NN * 65];
    __shared__ __align__(16) float c_lds[NN];
    __shared__ float qarr[NN];
    __shared__ float sarr[NN];

    const float* __restrict__ myrow = mail + ((size_t)b * NN + lane) * FF;
    float a[FF];
#pragma unroll
    for (int k = 0; k < 8; ++k) {
        const float4 v = reinterpret_cast<const float4*>(myrow)[k];
        a[4*k+0] = v.x; a[4*k+1] = v.y; a[4*k+2] = v.z; a[4*k+3] = v.w;
    }
    const float sn = src_norm[b * NN + lane];

    float q0 = 0.f, q1 = 0.f, q2 = 0.f, q3 = 0.f;
#pragma unroll
    for (int k = 0; k < 8; ++k) {
        q0 = fmaf(a[4*k+0], a[4*k+0], q0);
        q1 = fmaf(a[4*k+1], a[4*k+1], q1);
        q2 = fmaf(a[4*k+2], a[4*k+2], q2);
        q3 = fmaf(a[4*k+3], a[4*k+3], q3);
    }
    const float q = (q0 + q1) + (q2 + q3);

    float lg = 0.f;
#pragma unroll
    for (int f = 0; f < FF; ++f) lg = fmaf(a[f], attn_w[f], lg);
    lg *= sn;

    qarr[lane] = q;
    sarr[lane] = sn;
    __syncthreads();

    float mx = lg;
#pragma unroll
    for (int off = 32; off > 0; off >>= 1)
        mx = fmaxf(mx, __shfl_xor(mx, off, 64));
    const float ex = __expf(lg - mx);
    float se = ex;
#pragma unroll
    for (int off = 32; off > 0; off >>= 1)
        se += __shfl_xor(se, off, 64);
    const float attn = ex / se;

    const float sqn = sn * sn * q;
    float dsum = 0.f;
    for (int m = 0; m < NN; ++m) {
        const float4* __restrict__ Am =
            reinterpret_cast<const float4*>(mail + ((size_t)b * NN + m) * FF);
        float g0 = 0.f, g1 = 0.f, g2 = 0.f, g3 = 0.f;
#pragma unroll
        for (int k = 0; k < 8; ++k) {
            const float4 v = Am[k];
            g0 = fmaf(a[4*k+0], v.x, g0);
            g1 = fmaf(a[4*k+1], v.y, g1);
            g2 = fmaf(a[4*k+2], v.z, g2);
            g3 = fmaf(a[4*k+3], v.w, g3);
        }
        const float g  = (g0 + g1) + (g2 + g3);
        const float sm = sarr[m];
        const float qm = qarr[m];
        const float sqm = sm * sm * qm;
        const float d2  = (sqn - 2.f * (sn * sm) * g) + sqm;
        const float d   = sqrtf(fmaxf(d2, 0.f));
        dsum += d;
        sims[lane * 65 + m] = d;
    }

    float tot = dsum;
#pragma unroll
    for (int off = 32; off > 0; off >>= 1)
        tot += __shfl_xor(tot, off, 64);
    const float meand = tot * (1.f / (float)(NN * NN));
    const float inv   = -1.f / meand;   // SIGMA = 1

    float srow[NN];
#pragma unroll
    for (int m = 0; m < NN; ++m) {
        const float d = sims[lane * 65 + m];
        const float s = __expf(d * inv);
        srow[m] = s;
        sims[lane * 65 + m] = s;
    }
#pragma unroll
    for (int m = 0; m < NN; ++m)
        asm volatile("" : "+v"(srow[m]));

    c_lds[lane] = 0.f;
    float c_reg = 0.f;
    __syncthreads();   // sims s-values complete; c_lds initialized

    // ---- unconditional early spill (overlaps the greedy loop below) ----
    attn_g[b * NN + lane] = attn;
    {
        float* __restrict__ simsb = sims_g + (size_t)b * NN * NN;
        for (int m = 0; m < NN; ++m)
            simsb[m * NN + lane] = sims[m * 65 + lane];
    }

    int firstBelow = ITERS;

    for (int t = 0; t < ITERS; ++t) {
        float gain = 0.f;
#pragma unroll
        for (int k = 0; k < 16; ++k) {
            const float4 cv = reinterpret_cast<const float4*>(c_lds)[k];
            gain += fmaxf(srow[4*k+0] - cv.x, 0.f);
            gain += fmaxf(srow[4*k+1] - cv.y, 0.f);
            gain += fmaxf(srow[4*k+2] - cv.z, 0.f);
            gain += fmaxf(srow[4*k+3] - cv.w, 0.f);
        }
        gain *= attn;

        float gv = gain; int gi = lane;
#pragma unroll
        for (int off = 32; off > 0; off >>= 1) {
            const float ov = __shfl_xor(gv, off, 64);
            const int   oi = __shfl_xor(gi, off, 64);
            if (ov > gv || (ov == gv && oi < gi)) { gv = ov; gi = oi; }
        }

        if (lane == 0) sels_ws[(size_t)b * ITERS + t] = (unsigned char)gi;

        const float srl = sims[gi * 65 + lane];
        c_reg = fmaxf(c_reg, srl);
        c_lds[lane] = c_reg;
        __syncthreads();

        if (gv < THRESH) { firstBelow = t; break; }   // wave-uniform
    }

    if (lane == 0) {
        atomicMax(tmax_ws, firstBelow);
        tstop_ws[b] = firstBelow;
    }
}

// ---------------------------------------------------------------------------
// PASS B + ACCUM fused. Resume part unchanged from r8/r9 (passed): batches
// with fb < tEnd reconstruct c by exact fmax replay, then run the greedy body
// to tEnd. New selections go to sel_lds (LDS) -- nothing downstream reads
// sels_ws beyond what A wrote, since accum now lives here. Accum (lanes 0-31,
// all batches) is the exact r0 chain: C = min(48, Tmax+1), t-ascending fmaf.
// Non-resumed batches have tEnd <= fb, so accum reads only A's global sels.
// ---------------------------------------------------------------------------
__global__ __launch_bounds__(64) void gat_greedyB_acc_kernel(
    const float* __restrict__ sims_g,
    const float* __restrict__ attn_g,
    const float* __restrict__ mail,
    const float* __restrict__ src_norm,
    const float* __restrict__ dst_norm,
    const int* __restrict__ tmax_ws,
    const int* __restrict__ tstop_ws,
    const unsigned char* __restrict__ sels_ws,
    float* __restrict__ out)
{
    const int b = blockIdx.x;
    const int lane = threadIdx.x;

    const int fb   = tstop_ws[b];
    const int Tmax = *tmax_ws;
    const int tEnd = min(ITERS - 1, Tmax);   // last t whose selection is consumed

    __shared__ __align__(16) float c_lds[NN];
    __shared__ int sel_lds[ITERS];

    const unsigned char* __restrict__ sb = sels_ws + (size_t)b * ITERS;

    if (fb < tEnd) {   // block-uniform condition (barriers below are uniform)
        const float* __restrict__ simsb = sims_g + (size_t)b * NN * NN;

        float srow[NN];
        const float4* __restrict__ rp =
            reinterpret_cast<const float4*>(simsb + (size_t)lane * NN);
#pragma unroll
        for (int k = 0; k < 16; ++k) {
            const float4 v = rp[k];
            srow[4*k+0] = v.x; srow[4*k+1] = v.y;
            srow[4*k+2] = v.z; srow[4*k+3] = v.w;
        }
#pragma unroll
        for (int m = 0; m < NN; ++m)
            asm volatile("" : "+v"(srow[m]));

        const float attn = attn_g[b * NN + lane];

        // replay selections 0..fb to reconstruct c (fmax: exact)
        float c_reg = 0.f;
        for (int j = 0; j <= fb; ++j) {
            const int sel = sb[j];
            c_reg = fmaxf(c_reg, simsb[sel * NN + lane]);
        }
        c_lds[lane] = c_reg;
        __syncthreads();

        for (int t = fb + 1; t <= tEnd; ++t) {
            float gain = 0.f;
#pragma unroll
            for (int k = 0; k < 16; ++k) {
                const float4 cv = reinterpret_cast<const float4*>(c_lds)[k];
                gain += fmaxf(srow[4*k+0] - cv.x, 0.f);
                gain += fmaxf(srow[4*k+1] - cv.y, 0.f);
                gain += fmaxf(srow[4*k+2] - cv.z, 0.f);
                gain += fmaxf(srow[4*k+3] - cv.w, 0.f);
            }
            gain *= attn;

            float gv = gain; int gi = lane;
#pragma unroll
            for (int off = 32; off > 0; off >>= 1) {
                const float ov = __shfl_xor(gv, off, 64);
                const int   oi = __shfl_xor(gi, off, 64);
                if (ov > gv || (ov == gv && oi < gi)) { gv = ov; gi = oi; }
            }

            if (lane == 0) sel_lds[t] = gi;

            const float srl = simsb[gi * NN + lane];
            c_reg = fmaxf(c_reg, srl);
            c_lds[lane] = c_reg;
            __syncthreads();   // also publishes sel_lds[t] for the accum below
        }
    }

    // ---- accum (exact r0 chain), all batches, lanes 0..31 ----
    if (lane < FF) {
        const int C = min(ITERS, Tmax + 1);
        float acc = 0.f;
        for (int t = 0; t < C; ++t) {
            const int sel = (t <= fb) ? (int)sb[t] : sel_lds[t];
            acc = fmaf(mail[((size_t)b * NN + sel) * FF + lane],
                       src_norm[b * NN + sel], acc);
        }
        out[b * FF + lane] = acc * dst_norm[b];
    }
}

// ---------------------------------------------------------------------------
// ACCUM (proven r0 form) -- fallback path only
// ---------------------------------------------------------------------------
__global__ __launch_bounds__(64) void gat_accum_kernel(
    const float* __restrict__ mail,
    const float* __restrict__ src_norm,
    const float* __restrict__ dst_norm,
    const int* __restrict__ tmax_ws,
    const unsigned char* __restrict__ sels_ws,
    float* __restrict__ out)
{
    const int lane = threadIdx.x & 31;
    const int b = blockIdx.x * 2 + (threadIdx.x >> 5);
    const int C = min(ITERS, *tmax_ws + 1);
    const unsigned char* __restrict__ sb = sels_ws + (size_t)b * ITERS;
    float acc = 0.f;
    for (int t = 0; t < C; ++t) {
        const int sel = sb[t];
        acc = fmaf(mail[((size_t)b * NN + sel) * FF + lane],
                   src_norm[b * NN + sel], acc);
    }
    out[b * FF + lane] = acc * dst_norm[b];
}

extern "C" void kernel_launch(void* const* d_in, const int* in_sizes, int n_in,
                              void* d_out, int out_size, void* d_ws, size_t ws_size,
                              hipStream_t stream)
{
    const float* mail     = (const float*)d_in[0];
    const float* attn_w   = (const float*)d_in[1];
    const float* src_norm = (const float*)d_in[2];
    const float* dst_norm = (const float*)d_in[3];
    float* out = (float*)d_out;

    int* tmax_ws = (int*)d_ws;
    unsigned char* sels_ws = (unsigned char*)d_ws + 16;

    hipMemsetAsync(d_ws, 0, 4, stream);   // zero the Tmax word

    if (ws_size >= WS_NEEDED) {
        int*   tstop_ws = (int*)((char*)d_ws + TSTOP_OFF);
        float* attn_g   = (float*)((char*)d_ws + ATTN_OFF);
        float* sims_g   = (float*)((char*)d_ws + SIMS_OFF);
        gat_fusedA_kernel<<<dim3(B_TOT), dim3(64), 0, stream>>>(
            mail, attn_w, src_norm, tmax_ws, tstop_ws, sels_ws, sims_g, attn_g);
        gat_greedyB_acc_kernel<<<dim3(B_TOT), dim3(64), 0, stream>>>(
            sims_g, attn_g, mail, src_norm, dst_norm,
            tmax_ws, tstop_ws, sels_ws, out);
    } else {
        gat_greedy_kernel<<<dim3(B_TOT), dim3(64), 0, stream>>>(
            mail, attn_w, src_norm, tmax_ws, sels_ws);
        gat_accum_kernel<<<dim3(B_TOT / 2), dim3(64), 0, stream>>>(
            mail, src_norm, dst_norm, tmax_ws, sels_ws, out);
    }
}